// Round 8
// baseline (455.920 us; speedup 1.0000x reference)
//
#include <hip/hip_runtime.h>
#include <float.h>
#include <stdint.h>

#define NUM_CELLS 2048
#define CELL_DIM  256
#define N_STATES  131072

typedef _Float16 half8 __attribute__((ext_vector_type(8)));
typedef float    f32x4 __attribute__((ext_vector_type(4)));
typedef float    f32x4v __attribute__((ext_vector_type(4)));   // nt-load-able

// Stage-1 (1-pass fp16) sim-difference noise sigma ~6e-3; M1 ~ 17 sigma.
#define M1 0.10f
// Stage-2 (fp16x2 3-pass) noise sigma ~1.5e-5; M2 = 0.0008 ~ 50 sigma.
#define M2 0.0008f
#define CAP1 32768
#define CAP2 4096

// ws layout (bytes). ws_size >= WS_NEEDED confirmed (rounds 2-4 ran this path).
#define WS_C1 0
#define WS_C2 4
#define WS_L1 1024
#define WS_L2 (WS_L1 + 4 * CAP1)                    // 132096
#define WS_PH 262144
#define WS_PL (WS_PH + 1048576)
// 128 KB slack after pl retained (layout unchanged from verified rounds).
#define WS_NEEDED (WS_PL + 1048576 + 131072)        // 2490368

#define AS1 __attribute__((address_space(1)))
#define AS3 __attribute__((address_space(3)))

// ---------------------------------------------------------------------------
// Prep: p fp32 -> B-fragment-order fp16 hi + (lo*2048) arrays; zero counters.
// Frag order (16x16x32 f16 B): half8 index d = (ct*8 + kf)*64 + l, where
// cell = ct*16 + (l&15), k = kf*32 + (l>>4)*8 + j.
// ---------------------------------------------------------------------------
__global__ void prep_p(const float* __restrict__ p, _Float16* __restrict__ ph,
                       _Float16* __restrict__ pl, int* __restrict__ c1,
                       int* __restrict__ c2) {
    int d = blockIdx.x * 256 + threadIdx.x;   // 65536 dests
    if (d == 0) { *c1 = 0; *c2 = 0; }
    int l = d & 63, kf = (d >> 6) & 7, ct = d >> 9;
    int cell = ct * 16 + (l & 15);
    int k0 = kf * 32 + (l >> 4) * 8;
    const float* s = p + cell * 256 + k0;
    float4 a = *(const float4*)s, b = *(const float4*)(s + 4);
    float v[8] = {a.x, a.y, a.z, a.w, b.x, b.y, b.z, b.w};
    half8 h, lo;
#pragma unroll
    for (int j = 0; j < 8; ++j) {
        _Float16 hi = (_Float16)v[j];
        h[j] = hi;
        lo[j] = (_Float16)((v[j] - (float)hi) * 2048.0f);  // scaled: no fp16 denorms
    }
    *(half8*)(ph + (size_t)d * 8) = h;
    *(half8*)(pl + (size_t)d * 8) = lo;
}

// ---------------------------------------------------------------------------
// Kernel A (R8): 1-pass fp16 MFMA GEMM, 64 ROWS PER WAVE, 2 blocks/CU.
// R7 post-mortem: occupancy lever exhausted (3rd block: -4%); MfmaUtil
// pinned ~38% because the LDS READ pipe is at parity with the matrix pipe:
// all 4 waves of a block read the identical 16 KB slab (4x redundant), and
// one 4-SIMD barrier per 16 wave-MFMAs adds skew. R8 halves per-row costs:
//  - Wave owns 64 rows (A[4][8] = 128 VGPRs, the R0 footprint) -> chip-wide
//    LDS reads halve (2048 waves x 1 MB instead of 4096 x 1 MB); barriers
//    per unit work halve; 4 independent acc chains per burst (vs 2).
//  - Grid 512 = exactly 2 blocks/CU resident, one generation, no tail.
//  - Seal structure UNCHANGED from verified R7: 3 x 16 KB ring, stage
//    2-ahead via global_load_lds, in-place Bf rotation, ONE fused
//    "s_waitcnt vmcnt(4); s_barrier" per iteration placed MID-iteration.
// Seal ledger (4 loads/thread/stage; stage idx wraps &63):
//  top of t: issue stage(t+2) -> outstanding {t+1, t+2} = 8.
//  ct0 burst: refills read slab t ct1 (p0+8K) -- sealed at mid-(t-1). OK
//  mid-t fused wait: vmcnt(4) retires stage(t+1) in EVERY wave, then
//    s_barrier -> slab t+1 sealed for all waves. OK
//  ct1 burst: refills read slab t+1 ct0 (p1) -- sealed. OK
//  Reuse: stage at top of t writes slab t-1's buffer; last reads were iter
//    t-1's ct0 refills, before the mid-(t-1) barrier. OK
//  Prologue: stage 0,1; A-loads (converts drain all earlier vm loads --
//    conservative); fused vmcnt(4)+barrier seals slabs 0,1. Tail (t=62,63)
//    stages wrap copies into buffers whose subsequent refill-reads are
//    discarded (mapped, harmless); final vmcnt(0) drains.
// Arithmetic bit-identical to R5-R7 (same A loads/casts, same ph bytes,
// k-ascending chains, tracker update ct0-then-ct1 per ascending slab).
// ---------------------------------------------------------------------------
__launch_bounds__(256, 2)
__global__ void pc_gemm1(const float* __restrict__ x, const _Float16* __restrict__ ph,
                         int* __restrict__ out, int* __restrict__ c1,
                         int* __restrict__ l1) {
    __shared__ _Float16 ringmem[24576];   // 48 KB: 3 x 16 KB B slabs
    char* ring = (char*)ringmem;

    const int tid = threadIdx.x;
    const int l = tid & 63;
    const int w = tid >> 6;               // wave 0..3

    const char* phb = (const char*)ph;

    // Prologue: stage slabs 0,1 into bufs 0,1 (4 loads/thread each).
#pragma unroll
    for (int ss = 0; ss < 2; ++ss) {
        const char* src = phb + ss * 16384 + w * 4096 + (size_t)l * 16;
        char* dst = ring + ss * 16384 + w * 4096;
#pragma unroll
        for (int i = 0; i < 4; ++i)
            __builtin_amdgcn_global_load_lds((const AS1 void*)(src + i * 1024),
                                             (AS3 void*)(dst + i * 1024), 16, 0, 0);
    }

    // A-frags: 64 rows/wave, per-lane NT loads from x, fp16-convert in regs
    // (same addresses + rounding as all verified rounds).
    const int wrow = blockIdx.x * 256 + w * 64;
    half8 A[4][8];
#pragma unroll
    for (int rt = 0; rt < 4; ++rt)
#pragma unroll
        for (int kf = 0; kf < 8; ++kf) {
            const f32x4v* sp = (const f32x4v*)(x +
                (size_t)(wrow + rt * 16 + (l & 15)) * 256 + kf * 32 + (l >> 4) * 8);
            f32x4v a = __builtin_nontemporal_load(sp);
            f32x4v b = __builtin_nontemporal_load(sp + 1);
            half8 h;
            h[0] = (_Float16)a[0]; h[1] = (_Float16)a[1];
            h[2] = (_Float16)a[2]; h[3] = (_Float16)a[3];
            h[4] = (_Float16)b[0]; h[5] = (_Float16)b[1];
            h[6] = (_Float16)b[2]; h[7] = (_Float16)b[3];
            A[rt][kf] = h;
        }

    // Fused wait+barrier: stage-0/1 writes retired (A-converts already
    // drained them -- conservative) and sealed for all waves.
    asm volatile("s_waitcnt vmcnt(4)\n\ts_barrier" ::: "memory");

    // Preload slab 0's ct0 frags into the single Bf set.
    const int lofs = l * 16;
    half8 Bf[8];
#pragma unroll
    for (int k = 0; k < 8; ++k)
        Bf[k] = *(const half8*)(ring + k * 1024 + lofs);

    // Rotating buffer pointers: p0 = slab t, p1 = slab t+1, p2 = stage dest.
    char* p0 = ring;
    char* p1 = ring + 16384;
    char* p2 = ring + 32768;

    // Trackers: 16 per lane (rt*4+reg rows); ic encodes slab*2+ct.
    float t1[16], t2[16];
    int ic[16];
#pragma unroll
    for (int s = 0; s < 16; ++s) { t1[s] = -FLT_MAX; t2[s] = -FLT_MAX; ic[s] = 0; }

#define UPD2(V, TR, CODE)                                                  \
    {                                                                      \
        float v = (V);                                                     \
        float nt2 = __builtin_amdgcn_fmed3f(t1[TR], t2[TR], v);            \
        ic[TR] = (v > t1[TR]) ? (CODE) : ic[TR];                           \
        t1[TR] = fmaxf(t1[TR], v);                                         \
        t2[TR] = nt2;                                                      \
    }

    for (int t = 0; t < 64; ++t) {
        // Stage slab (t+2)&63 -> p2 (slab t-1's buffer; its last reads were
        // iter t-1's ct0 refills, before the mid-(t-1) barrier).
        {
            int tn = (t + 2) & 63;
            const char* src = phb + (size_t)tn * 16384 + w * 4096 + (size_t)l * 16;
#pragma unroll
            for (int i = 0; i < 4; ++i)
                __builtin_amdgcn_global_load_lds((const AS1 void*)(src + i * 1024),
                                                 (AS3 void*)(p2 + w * 4096 + i * 1024),
                                                 16, 0, 0);
        }

        // ct0 burst: 4 chains x 8; refill Bf[k] <- slab t's ct1 frag k
        // (p0+8K, sealed at mid-(t-1)) right after its last use this slab.
        f32x4 a00 = {}, a10 = {}, a20 = {}, a30 = {};
#pragma unroll
        for (int k = 0; k < 8; ++k) {
            a00 = __builtin_amdgcn_mfma_f32_16x16x32_f16(A[0][k], Bf[k], a00, 0, 0, 0);
            a10 = __builtin_amdgcn_mfma_f32_16x16x32_f16(A[1][k], Bf[k], a10, 0, 0, 0);
            a20 = __builtin_amdgcn_mfma_f32_16x16x32_f16(A[2][k], Bf[k], a20, 0, 0, 0);
            a30 = __builtin_amdgcn_mfma_f32_16x16x32_f16(A[3][k], Bf[k], a30, 0, 0, 0);
            Bf[k] = *(const half8*)(p0 + 8192 + k * 1024 + lofs);
        }
#pragma unroll
        for (int reg = 0; reg < 4; ++reg) {
            UPD2(a00[reg], reg,      t * 2)
            UPD2(a10[reg], 4 + reg,  t * 2)
            UPD2(a20[reg], 8 + reg,  t * 2)
            UPD2(a30[reg], 12 + reg, t * 2)
        }

        // THE seal point (one per iteration): every wave retires ITS
        // stage(t+1) loads (outstanding {t+1,t+2}=8 -> vmcnt(4)), then the
        // barrier makes slab t+1 visible to ALL waves. Stage(t+2) rides
        // across the barrier (never vmcnt(0) in-loop).
        asm volatile("s_waitcnt vmcnt(4)\n\ts_barrier" ::: "memory");

        // ct1 burst: refill Bf[k] <- slab t+1's ct0 frag k (p1, just sealed).
        f32x4 a01 = {}, a11 = {}, a21 = {}, a31 = {};
#pragma unroll
        for (int k = 0; k < 8; ++k) {
            a01 = __builtin_amdgcn_mfma_f32_16x16x32_f16(A[0][k], Bf[k], a01, 0, 0, 0);
            a11 = __builtin_amdgcn_mfma_f32_16x16x32_f16(A[1][k], Bf[k], a11, 0, 0, 0);
            a21 = __builtin_amdgcn_mfma_f32_16x16x32_f16(A[2][k], Bf[k], a21, 0, 0, 0);
            a31 = __builtin_amdgcn_mfma_f32_16x16x32_f16(A[3][k], Bf[k], a31, 0, 0, 0);
            Bf[k] = *(const half8*)(p1 + k * 1024 + lofs);
        }
#pragma unroll
        for (int reg = 0; reg < 4; ++reg) {
            UPD2(a01[reg], reg,      t * 2 + 1)
            UPD2(a11[reg], 4 + reg,  t * 2 + 1)
            UPD2(a21[reg], 8 + reg,  t * 2 + 1)
            UPD2(a31[reg], 12 + reg, t * 2 + 1)
        }

        // Rotate ring pointers (no bottom barrier: reuse is sealed mid-iter).
        char* tp = p0; p0 = p1; p1 = p2; p2 = tp;
    }
#undef UPD2

    // Drain wrap-tail stages (writes to dead buffers) before LDS dealloc.
    asm volatile("s_waitcnt vmcnt(0)" ::: "memory");

    // Butterfly across the 16 column lanes (masks < 16 keep l>>4 fixed).
    int idx[16];
#pragma unroll
    for (int s = 0; s < 16; ++s) idx[s] = ic[s] * 16 + (l & 15);   // global cell
#pragma unroll
    for (int m = 1; m <= 8; m <<= 1) {
#pragma unroll
        for (int s = 0; s < 16; ++s) {
            float ot1 = __shfl_xor(t1[s], m, 64);
            int   oi  = __shfl_xor(idx[s], m, 64);
            float ot2 = __shfl_xor(t2[s], m, 64);
            float nt2 = fmaxf(fminf(t1[s], ot1), fmaxf(t2[s], ot2));
            if (ot1 > t1[s] || (ot1 == t1[s] && oi < idx[s])) { t1[s] = ot1; idx[s] = oi; }
            t2[s] = nt2;
        }
    }

    // Epilogue: lanes with (l&15)==0 own row = wrow + rt*16 + (l>>4)*4 + reg.
    // No cross-wave combine needed (wave owns its rows for ALL cells).
#pragma unroll
    for (int s = 0; s < 16; ++s) {
        int rt = s >> 2, reg = s & 3;
        int row = wrow + rt * 16 + (l >> 4) * 4 + reg;
        bool vld = (l & 15) == 0;
        if (vld) out[row] = idx[s];
        bool f = vld && (t1[s] - t2[s] < M1);
        unsigned long long msk = __ballot(f);
        int cnt = __popcll(msk);
        if (cnt) {   // wave-uniform
            int prefix = __popcll(msk & ((1ull << l) - 1ull));
            int bpos = 0;
            if (l == 0) bpos = atomicAdd(c1, cnt);
            bpos = __shfl(bpos, 0, 64);
            if (f) {
                int pos = bpos + prefix;
                if (pos < CAP1) l1[pos] = row;
            }
        }
    }
}

// ---------------------------------------------------------------------------
// Kernel B: fp16x2 3-pass MFMA on flagged rows, barrier-free K-loop.
// Grid-stride over 16-row groups (grid 256). 256 thr = 4 waves (wc = col
// group). Per-sim arithmetic IDENTICAL to rounds 3-4 (verified absmax 0).
// ---------------------------------------------------------------------------
__launch_bounds__(256, 2)
__global__ void pc_rescue2(const float* __restrict__ x, const _Float16* __restrict__ ph,
                           const _Float16* __restrict__ pl,
                           const int* __restrict__ c1, const int* __restrict__ l1,
                           int* __restrict__ out, int* __restrict__ c2,
                           int* __restrict__ l2) {
    const int n0 = *c1;
    const int n = n0 < CAP1 ? n0 : CAP1;
    const int G = (n + 15) >> 4;
    const int tid = threadIdx.x;
    const int l = tid & 63, wc = tid >> 6;

    __shared__ float rT1[64];
    __shared__ int   rI1[64];
    __shared__ float rT2[64];

    for (int g = blockIdx.x; g < G; g += gridDim.x) {
        const int base = g * 16;
        __syncthreads();   // protect shared reuse across group iterations

        const int rslot = base + (l & 15);
        const int my_row = l1[rslot < n ? rslot : (n - 1)];

        half8 Ah[8], Al[8];
#pragma unroll
        for (int kf = 0; kf < 8; ++kf) {
            const float* s = x + (size_t)my_row * 256 + kf * 32 + (l >> 4) * 8;
            float4 a = *(const float4*)s, b = *(const float4*)(s + 4);
            float v[8] = {a.x, a.y, a.z, a.w, b.x, b.y, b.z, b.w};
#pragma unroll
            for (int j = 0; j < 8; ++j) {
                _Float16 hi = (_Float16)v[j];
                Ah[kf][j] = hi;
                Al[kf][j] = (_Float16)((v[j] - (float)hi) * 2048.0f);
            }
        }

        const _Float16* bh = ph + wc * 4096 + (size_t)l * 8;
        const _Float16* bl = pl + wc * 4096 + (size_t)l * 8;
        half8 BH[4], BL[4];
#pragma unroll
        for (int j = 0; j < 4; ++j) {
            BH[j] = *(const half8*)(bh + j * 512);
            BL[j] = *(const half8*)(bl + j * 512);
        }

        float t1[4], t2[4];
        int ic[4];
#pragma unroll
        for (int s = 0; s < 4; ++s) { t1[s] = -FLT_MAX; t2[s] = -FLT_MAX; ic[s] = 0; }

        for (int t = 0; t < 32; ++t) {
            const _Float16* bth = bh + t * 16384;
            const _Float16* btl = bl + t * 16384;
            f32x4 hh = {}, hl = {}, lh = {};
#pragma unroll
            for (int k = 0; k < 8; ++k) {
                half8 Bh_ = BH[k & 3], Bl_ = BL[k & 3];
                int off = (k < 4) ? (k + 4) * 512 : (16384 + (k - 4) * 512);
                BH[k & 3] = *(const half8*)(bth + off);
                BL[k & 3] = *(const half8*)(btl + off);
                hh = __builtin_amdgcn_mfma_f32_16x16x32_f16(Ah[k], Bh_, hh, 0, 0, 0);
                hl = __builtin_amdgcn_mfma_f32_16x16x32_f16(Ah[k], Bl_, hl, 0, 0, 0);
                lh = __builtin_amdgcn_mfma_f32_16x16x32_f16(Al[k], Bh_, lh, 0, 0, 0);
            }
#pragma unroll
            for (int reg = 0; reg < 4; ++reg) {
                float v = hh[reg] + (hl[reg] + lh[reg]) * (1.0f / 2048.0f);
                float nt2 = __builtin_amdgcn_fmed3f(t1[reg], t2[reg], v);
                ic[reg] = (v > t1[reg]) ? t : ic[reg];
                t1[reg] = fmaxf(t1[reg], v);
                t2[reg] = nt2;
            }
        }

        int idx[4];
#pragma unroll
        for (int s = 0; s < 4; ++s) idx[s] = (ic[s] * 4 + wc) * 16 + (l & 15);
#pragma unroll
        for (int m = 1; m <= 8; m <<= 1) {
#pragma unroll
            for (int s = 0; s < 4; ++s) {
                float ot1 = __shfl_xor(t1[s], m, 64);
                int   oi  = __shfl_xor(idx[s], m, 64);
                float ot2 = __shfl_xor(t2[s], m, 64);
                float nt2 = fmaxf(fminf(t1[s], ot1), fmaxf(t2[s], ot2));
                if (ot1 > t1[s] || (ot1 == t1[s] && oi < idx[s])) { t1[s] = ot1; idx[s] = oi; }
                t2[s] = nt2;
            }
        }

        if ((l & 15) == 0) {
#pragma unroll
            for (int reg = 0; reg < 4; ++reg) {
                int r = (l >> 4) * 4 + reg;
                rT1[r * 4 + wc] = t1[reg];
                rI1[r * 4 + wc] = idx[reg];
                rT2[r * 4 + wc] = t2[reg];
            }
        }
        __syncthreads();
        if (tid < 16) {
            float T1 = -FLT_MAX, T2 = -FLT_MAX; int I1 = 0x7FFFFFFF;
#pragma unroll
            for (int q = 0; q < 4; ++q) {
                float v1 = rT1[tid * 4 + q];
                int   vi = rI1[tid * 4 + q];
                float v2 = rT2[tid * 4 + q];
                float nt2 = fmaxf(fminf(T1, v1), fmaxf(T2, v2));
                if (v1 > T1 || (v1 == T1 && vi < I1)) { T1 = v1; I1 = vi; }
                T2 = nt2;
            }
            int slot = base + tid;
            if (slot < n) {
                int grow = l1[slot];
                out[grow] = I1;
                if (T1 - T2 < M2) {
                    int pos = atomicAdd(c2, 1);
                    if (pos < CAP2) l2[pos] = grow;
                }
            }
        }
    }
}

// ---------------------------------------------------------------------------
// Kernel C: exact fp32 argmax for residual rows (expected ~30).
// UNCHANGED arithmetic from rounds 2-4 (matches numpy on this dataset).
// ---------------------------------------------------------------------------
__global__ void rescue3(const float* __restrict__ x, const float* __restrict__ p,
                        const int* __restrict__ count, const int* __restrict__ list,
                        int* __restrict__ out) {
    __shared__ float xrow[256];
    __shared__ float pch[32][260];
    __shared__ float red2[32][9];
    __shared__ float bvs[32];
    __shared__ int   bis[32];
    const int tid = threadIdx.x;
    const int n0 = *count;
    const int n = n0 < CAP2 ? n0 : CAP2;
    for (int e = blockIdx.x; e < n; e += gridDim.x) {
        const int row = list[e];
        __syncthreads();
        if (tid < 64) {
            float4 v = *(const float4*)(x + (size_t)row * 256 + tid * 4);
            *(float4*)(&xrow[tid * 4]) = v;
        }
        float bv = -FLT_MAX; int bi = 0;
        const int cell = tid & 31, kq = tid >> 5;
        for (int c0 = 0; c0 < NUM_CELLS; c0 += 32) {
            __syncthreads();
#pragma unroll
            for (int i = 0; i < 8; ++i) {
                int f = tid + i * 256;
                int cr = f >> 6, k4 = (f & 63) * 4;
                float4 v = *(const float4*)(p + (size_t)(c0 + cr) * 256 + k4);
                *(float4*)(&pch[cr][k4]) = v;
            }
            __syncthreads();
            float s = 0.f;
#pragma unroll
            for (int j = 0; j < 8; ++j) {
                float4 pv = *(const float4*)(&pch[cell][kq * 32 + j * 4]);
                float4 xv = *(const float4*)(&xrow[kq * 32 + j * 4]);
                s = fmaf(xv.x, pv.x, s); s = fmaf(xv.y, pv.y, s);
                s = fmaf(xv.z, pv.z, s); s = fmaf(xv.w, pv.w, s);
            }
            red2[cell][kq] = s;
            __syncthreads();
            if (tid < 32) {
                float dot = 0.f;
#pragma unroll
                for (int q = 0; q < 8; ++q) dot += red2[tid][q];
                if (dot > bv) { bv = dot; bi = c0 + tid; }
            }
        }
        if (tid < 32) { bvs[tid] = bv; bis[tid] = bi; }
        __syncthreads();
        if (tid == 0) {
            float B = bvs[0]; int BI = bis[0];
#pragma unroll
            for (int t = 1; t < 32; ++t)
                if (bvs[t] > B || (bvs[t] == B && bis[t] < BI)) { B = bvs[t]; BI = bis[t]; }
            out[row] = BI;
        }
    }
}

// ---------------------------------------------------------------------------
// Fallback (round-1 fp32 vector path) if ws too small.
// ---------------------------------------------------------------------------
#define BM 64
#define BN 64
#define BK 32
#define XP 260
#define PP 68
__launch_bounds__(256, 2)
__global__ void placecells_argmax_fp32(const float* __restrict__ x,
                                       const float* __restrict__ pc,
                                       int* __restrict__ out) {
    __shared__ float xs[BM * XP];
    __shared__ float ps[BK * PP];
    const int tid = threadIdx.x;
    const int tx = tid & 15;
    const int ty = tid >> 4;
    const float* xg = x + (size_t)blockIdx.x * (BM * CELL_DIM);
#pragma unroll
    for (int i = 0; i < 16; ++i) {
        int f = tid + i * 256;
        int s = f >> 6, k4 = (f & 63) << 2;
        *(float4*)(&xs[s * XP + k4]) = *(const float4*)(xg + s * CELL_DIM + k4);
    }
    __syncthreads();
    float runv[4]; int runi[4];
#pragma unroll
    for (int si = 0; si < 4; ++si) { runv[si] = -FLT_MAX; runi[si] = 0; }
    for (int jc = 0; jc < NUM_CELLS; jc += BN) {
        float acc[4][4];
#pragma unroll
        for (int si = 0; si < 4; ++si)
#pragma unroll
            for (int cj = 0; cj < 4; ++cj) acc[si][cj] = 0.0f;
        for (int kc = 0; kc < CELL_DIM; kc += BK) {
            __syncthreads();
#pragma unroll
            for (int i = 0; i < 2; ++i) {
                int f = tid + i * 256;
                int c = f >> 3, k4 = (f & 7) << 2;
                float4 v = *(const float4*)(pc + (size_t)(jc + c) * CELL_DIM + kc + k4);
                ps[(k4 + 0) * PP + c] = v.x; ps[(k4 + 1) * PP + c] = v.y;
                ps[(k4 + 2) * PP + c] = v.z; ps[(k4 + 3) * PP + c] = v.w;
            }
            __syncthreads();
#pragma unroll
            for (int kk = 0; kk < BK; kk += 4) {
                float4 xv[4];
#pragma unroll
                for (int si = 0; si < 4; ++si)
                    xv[si] = *(const float4*)(&xs[(ty * 4 + si) * XP + kc + kk]);
#pragma unroll
                for (int kt = 0; kt < 4; ++kt) {
                    float4 pv = *(const float4*)(&ps[(kk + kt) * PP + tx * 4]);
#pragma unroll
                    for (int si = 0; si < 4; ++si) {
                        float xk = (kt == 0) ? xv[si].x : (kt == 1) ? xv[si].y :
                                   (kt == 2) ? xv[si].z : xv[si].w;
                        acc[si][0] = fmaf(xk, pv.x, acc[si][0]);
                        acc[si][1] = fmaf(xk, pv.y, acc[si][1]);
                        acc[si][2] = fmaf(xk, pv.z, acc[si][2]);
                        acc[si][3] = fmaf(xk, pv.w, acc[si][3]);
                    }
                }
            }
        }
#pragma unroll
        for (int si = 0; si < 4; ++si)
#pragma unroll
            for (int cj = 0; cj < 4; ++cj) {
                int idx = jc + tx * 4 + cj;
                if (acc[si][cj] > runv[si]) { runv[si] = acc[si][cj]; runi[si] = idx; }
            }
    }
    __syncthreads();
    float* rv = ps; int* ri = (int*)(ps + 1024);
#pragma unroll
    for (int si = 0; si < 4; ++si) {
        int s = ty * 4 + si;
        rv[s * 16 + tx] = runv[si]; ri[s * 16 + tx] = runi[si];
    }
    __syncthreads();
    if (tid < BM) {
        float bv = rv[tid * 16]; int bi = ri[tid * 16];
#pragma unroll
        for (int t = 1; t < 16; ++t) {
            float v = rv[tid * 16 + t]; int i = ri[tid * 16 + t];
            if (v > bv || (v == bv && i < bi)) { bv = v; bi = i; }
        }
        out[(size_t)blockIdx.x * BM + tid] = bi;
    }
}

extern "C" void kernel_launch(void* const* d_in, const int* in_sizes, int n_in,
                              void* d_out, int out_size, void* d_ws, size_t ws_size,
                              hipStream_t stream) {
    const float* x  = (const float*)d_in[0];   // (131072, 256) fp32
    const float* pc = (const float*)d_in[1];   // (2048, 256) fp32
    int* out = (int*)d_out;

    if (ws_size >= (size_t)WS_NEEDED) {
        char* ws = (char*)d_ws;
        int* c1 = (int*)(ws + WS_C1);
        int* c2 = (int*)(ws + WS_C2);
        int* l1 = (int*)(ws + WS_L1);
        int* l2 = (int*)(ws + WS_L2);
        _Float16* ph = (_Float16*)(ws + WS_PH);
        _Float16* pl = (_Float16*)(ws + WS_PL);
        prep_p<<<256, 256, 0, stream>>>(pc, ph, pl, c1, c2);
        pc_gemm1<<<N_STATES / 256, 256, 0, stream>>>(x, ph, out, c1, l1);
        pc_rescue2<<<256, 256, 0, stream>>>(x, ph, pl, c1, l1, out, c2, l2);
        rescue3<<<64, 256, 0, stream>>>(x, pc, c2, l2, out);
    } else {
        placecells_argmax_fp32<<<N_STATES / BM, 256, 0, stream>>>(x, pc, out);
    }
}